// Round 13
// baseline (8390.575 us; speedup 1.0000x reference)
//
#include <hip/hip_runtime.h>

#define NUM_ITERS 15
#define BB 2
#define NN 2048
#define QQ 256
#define CHUNKS 16          // colsum n-chunks of 128 rows

// ---------------------------------------------------------------------------
// Numerical contract (matches numpy-fp32 golden; verified absmax 0.00195 —
// LOAD-BEARING, do not relax):
//  - no FMA contraction (pragma clang fp contract(off))
//  - GEMM per output element: single fp32 accumulator, strictly ascending k,
//    round(mul) then round(add), final true division by max(sum,1)
//  - row reductions over q=256: numpy pairwise tree, order replicated exactly
//  - colsum: ascending-n in 16 chunks, combined ascending
//
// R4: gfx950 VGPR max=256; uncapped bounds + big unrolls -> scratch spill.
// R5: 1 wave/SIMD latency-bound under COMPILER scheduling.
// R6: counted waitcnt regions need "memory" clobbers + sched_barrier fences.
// R7: counted-lgkm 4x2/8-wave at the ~74-85 B/cyc/CU LDS-pipe ceiling.
// R8/R9: 4-wave configs cap ~45 B/cyc regardless of depth.
// R10: asm-pinned 72-reg rotating files crash/break counted vmcnt.
// R11: plain-C++ register pipelines get collapsed by regalloc (VGPR 56).
// R12: 64x32 x 2 blocks/CU = 3775us total, top gemm 145us, ~85% of the
//      123us LDS floor for the W+H-in-LDS structure.
// R13 (this round): H OFF the LDS pipe — W stays LDS-staged (counted lgkm),
//      H loaded direct from global (L1-resident 8KB/tile) via counted vmcnt,
//      depth-2, 24 pinned regs. LDS bytes/kk drop 24->16 B/lane: floor
//      123 -> 82-95us. H bits identical; chain untouched.
// ---------------------------------------------------------------------------

typedef float f4v __attribute__((ext_vector_type(4)));
typedef float f2v __attribute__((ext_vector_type(2)));
typedef __attribute__((address_space(3))) const float4 lds_cf4;

#define DSR128(d, a, IMM) asm volatile("ds_read_b128 %0, %1 offset:" #IMM : "=v"(d) : "v"(a) : "memory")
#define LGKM(N)           asm volatile("s_waitcnt lgkmcnt(" #N ")" ::: "memory")
// H direct load: 64-bit per-lane address in a VGPR pair, 13-bit signed imm
#define GL2(d, a, IMM)    asm volatile("global_load_dwordx2 %0, %1, off offset:" #IMM : "=v"(d) : "v"(a) : "memory")
#define VMC(N)            asm volatile("s_waitcnt vmcnt(" #N ")" ::: "memory")

__global__ __launch_bounds__(256) void colsum_part(
    const float* __restrict__ adj, const float* __restrict__ act,
    float* __restrict__ pe0, float* __restrict__ pi0,
    float* __restrict__ pe1, float* __restrict__ pi1)
{
#pragma clang fp contract(off)
    const int b = (int)blockIdx.z;
    const int c = (int)blockIdx.y;
    const int m = (int)blockIdx.x * 256 + (int)threadIdx.x;
    const float* src = adj + (size_t)b * NN * NN;
    const float* ab  = act + (size_t)b * NN;
    float se0 = 0.0f, si0 = 0.0f, se1 = 0.0f, si1 = 0.0f;
    const int n0 = c * (NN / CHUNKS);
    for (int n = n0; n < n0 + NN / CHUNKS; ++n) {
        float x = src[(size_t)n * NN + m];
        float e = (x > 0.5f) ? x : 0.0f;
        float v = 1.0f - x;
        float iv = (v > 0.5f) ? v : 0.0f;
        float av = ab[n];
        se1 = se1 + e;
        si1 = si1 + iv;
        se0 = se0 + e * av;
        si0 = si0 + iv * av;
    }
    size_t o = ((size_t)c * BB + b) * NN + m;
    pe0[o] = se0; pi0[o] = si0; pe1[o] = se1; pi1[o] = si1;
}

__global__ __launch_bounds__(256) void colsum_combine(
    const float* __restrict__ pe0, const float* __restrict__ pi0,
    const float* __restrict__ pe1, const float* __restrict__ pi1,
    float* __restrict__ se0, float* __restrict__ si0,
    float* __restrict__ se1, float* __restrict__ si1)
{
#pragma clang fp contract(off)
    const int i = (int)blockIdx.x * 256 + (int)threadIdx.x;   // 0..BB*NN-1
    float a = 0.0f, bb = 0.0f, cc = 0.0f, dd = 0.0f;
    for (int c = 0; c < CHUNKS; ++c) {
        size_t o = (size_t)c * (BB * NN) + i;
        a  = a  + pe0[o];
        bb = bb + pi0[o];
        cc = cc + pe1[o];
        dd = dd + pi1[o];
    }
    se0[i] = a; si0[i] = bb; se1[i] = cc; si1[i] = dd;
}

// ---------------------------------------------------------------------------
// Fused thresholded GEMM, np-fp32-exact per-element chain:
//   C[m][q] = sum_k (thr(adj[k][m]) * act[k]) * hsrc[k][q]   (ascending k)
//   mode 0: dst = h_old + C/max(sum,1);  mode 1: dst = C/max(sum,1)
//
// v13: 64x32 tile, BK=64, 256 threads (4 waves), 4x2 microtile.
//  - W: LDS double-buffered, threshold+act at staging, counted-lgkm
//    pipeline (16 groups of 4 kk; issue next group's 4 ds_read_b128,
//    lgkmcnt(4), sched_barrier, MACs). R12-proven.
//  - H: DIRECT global loads in the compute loop, counted vmcnt, depth-2
//    (issue group g+2's 4 global_load_dwordx2, vmcnt(8)); 3 rotating
//    slots (24 pinned regs). Per-tile H = 8KB -> L1-resident.
//  - The 4 W-staging global loads are older than all H loads; the first
//    vmcnt wait per tile forces them complete (~250cy/tile, ~3us, partly
//    hidden by the co-resident block). Accepted.
// Grid 512 = 2 independent blocks/CU, LDS 34816 B/block.
// ---------------------------------------------------------------------------
__global__ __launch_bounds__(256, 4) void gemm_fused(
    const float* __restrict__ adj,
    const float* __restrict__ hsrc,
    const float* act,
    const float* __restrict__ sums,
    const float* h_old,
    float* __restrict__ dst,
    int mode)
{
#pragma clang fp contract(off)
    __shared__ float4 W2[2][64][17];   // [dbuf][kk][16 f4 m-cols +pad] row=272B

    const int b  = (int)blockIdx.z;
    const int m0 = (int)blockIdx.x * 64;
    const int q0 = (int)blockIdx.y * 32;
    const int tid = (int)threadIdx.x;
    const int tq  = tid & 15;      // q-group: cols q0 + tq*2 .. +1
    const int tm  = tid >> 4;      // m-group: rows m0 + tm*4 .. +3

    const float* adjb = adj + (size_t)b * NN * NN;
    const float* hb   = hsrc + (size_t)b * NN * QQ;
    const float* ab   = (act != 0) ? (act + (size_t)b * NN) : (const float*)0;

    // LDS byte offset (addrspace(3)) for W reads
    const unsigned wbase = (unsigned)(uintptr_t)(lds_cf4*)&W2[0][0][0] + (unsigned)tm * 16u;
    // per-lane global byte address of h[0][q0 + tq*2]
    const unsigned long long hb64 = (unsigned long long)(uintptr_t)(hb + q0 + tq * 2);

    float acc[4][2];
    #pragma unroll
    for (int i = 0; i < 4; ++i)
        #pragma unroll
        for (int j = 0; j < 2; ++j)
            acc[i][j] = 0.0f;

    float4 wreg[4];

    // issue global loads for W K-tile starting at kbase into regs
    auto stage_load = [&](int kbase) {
#pragma clang fp contract(off)
        #pragma unroll
        for (int j = 0; j < 4; ++j) {          // W: 64kk x 16 seg = 1024 f4
            int idx = tid + j * 256;
            int kk  = idx >> 4;                // 0..63
            int seg = idx & 15;                // 0..15
            wreg[j] = *(const float4*)(adjb + (size_t)(kbase + kk) * NN + m0 + seg * 4);
        }
    };

    // threshold + write regs -> LDS buffer sbuf (kbase for act indexing)
    auto stage_store = [&](int sbuf, int kbase) {
#pragma clang fp contract(off)
        #pragma unroll
        for (int j = 0; j < 4; ++j) {
            int idx = tid + j * 256;
            int kk  = idx >> 4;
            int seg = idx & 15;
            float4 x = wreg[j];
            float4 w;
            if (mode == 0) {
                w.x = (x.x > 0.5f) ? x.x : 0.0f;
                w.y = (x.y > 0.5f) ? x.y : 0.0f;
                w.z = (x.z > 0.5f) ? x.z : 0.0f;
                w.w = (x.w > 0.5f) ? x.w : 0.0f;
            } else {
                float vx = 1.0f - x.x; w.x = (vx > 0.5f) ? vx : 0.0f;
                float vy = 1.0f - x.y; w.y = (vy > 0.5f) ? vy : 0.0f;
                float vz = 1.0f - x.z; w.z = (vz > 0.5f) ? vz : 0.0f;
                float vw = 1.0f - x.w; w.w = (vw > 0.5f) ? vw : 0.0f;
            }
            if (ab != 0) {
                float av = ab[kbase + kk];
                w.x = w.x * av; w.y = w.y * av; w.z = w.z * av; w.w = w.w * av;
            }
            W2[sbuf][kk][seg] = w;
        }
    };

    // compute one K-tile: W from LDS (counted lgkm, depth-1 groups of 4),
    // H direct from global (counted vmcnt, depth-2, 3 rotating slots).
    auto compute = [&](int cbuf, int k0) {
#pragma clang fp contract(off)
        __builtin_amdgcn_sched_barrier(0);     // fence: nothing enters region
        const unsigned wa = wbase + (unsigned)cbuf * 17408u;
        const unsigned long long ha0 = hb64 + (unsigned long long)k0 * 1024ull;
        f4v w[2][4];
        f2v h[3][4];
        // W prologue: group 0 (kk 0..3) into set 0
        DSR128(w[0][0], wa, 0);   DSR128(w[0][1], wa, 272);
        DSR128(w[0][2], wa, 544); DSR128(w[0][3], wa, 816);
        // H prologue: groups 0,1 (kk 0..7) into slots 0,1
        {
            unsigned long long a0 = ha0;
            GL2(h[0][0], a0, 0); GL2(h[0][1], a0, 1024);
            GL2(h[0][2], a0, 2048); GL2(h[0][3], a0, 3072);
            unsigned long long a1 = ha0 + 4096ull;
            GL2(h[1][0], a1, 0); GL2(h[1][1], a1, 1024);
            GL2(h[1][2], a1, 2048); GL2(h[1][3], a1, 3072);
        }
        #pragma unroll
        for (int g = 0; g < 16; ++g) {
            const int s = g & 1, sn = s ^ 1;
            const int hs = g % 3;
            if (g < 15) {
                unsigned awn = wa + (unsigned)((g + 1) * 1088);
                DSR128(w[sn][0], awn, 0);   DSR128(w[sn][1], awn, 272);
                DSR128(w[sn][2], awn, 544); DSR128(w[sn][3], awn, 816);
            }
            if (g < 14) {
                const int hn = (g + 2) % 3;
                unsigned long long an = ha0 + (unsigned long long)(g + 2) * 4096ull;
                GL2(h[hn][0], an, 0); GL2(h[hn][1], an, 1024);
                GL2(h[hn][2], an, 2048); GL2(h[hn][3], an, 3072);
            }
            if (g < 15) { LGKM(4); } else { LGKM(0); }
            if (g < 14) { VMC(8); } else if (g == 14) { VMC(4); } else { VMC(0); }
            __builtin_amdgcn_sched_barrier(0); // MACs stay below the waits
            #pragma unroll
            for (int j = 0; j < 4; ++j) {      // kk = 4g+j, ascending
                f4v wv = w[s][j];
                f2v hv = h[hs][j];
                #pragma unroll
                for (int i = 0; i < 4; ++i) {
                    acc[i][0] = acc[i][0] + wv[i] * hv[0];
                    acc[i][1] = acc[i][1] + wv[i] * hv[1];
                }
            }
        }
        __builtin_amdgcn_sched_barrier(0);     // fence: nothing leaves region
    };

    // prologue: W tile 0 into LDS buffer 0
    stage_load(0);
    stage_store(0, 0);
    __syncthreads();

    int cur = 0;
    #pragma clang loop unroll(disable)
    for (int k0 = 0; k0 < NN; k0 += 64) {
        const int knext = k0 + 64;
        if (knext < NN) stage_load(knext);     // W VMEM issue (oldest vm ops)
        compute(cur, k0);
        if (knext < NN) {
            stage_store(cur ^ 1, knext);       // writes the OTHER buffer
            __syncthreads();                   // one barrier per tile
            cur ^= 1;
        }
    }

    // epilogue: true division, optional h_old add, float2 stores
    #pragma unroll
    for (int i = 0; i < 4; ++i) {
        int row = m0 + tm * 4 + i;
        float s = sums[b * NN + row];
        if (s < 1.0f) s = 1.0f;
        float v0 = acc[i][0] / s;
        float v1 = acc[i][1] / s;
        size_t g = ((size_t)b * NN + row) * QQ + q0 + tq * 2;
        float2 o;
        if (mode == 0) {
            float2 ho = *(const float2*)(h_old + g);
            o.x = ho.x + v0; o.y = ho.y + v1;
        } else {
            o.x = v0; o.y = v1;
        }
        *(float2*)(dst + g) = o;
    }
}

// ---------------------------------------------------------------------------
// Projection + relu + L2-normalize, np-fp32-exact, in place on h_io.
// ---------------------------------------------------------------------------
__global__ __launch_bounds__(256) void project_kernel(
    float* h_io, const float* __restrict__ ieff)
{
#pragma clang fp contract(off)
    __shared__ float sp[256];
    __shared__ float sq[256];
    __shared__ float rs[32];
    __shared__ float sc[2];
    const int b = (int)blockIdx.y;
    const int m = (int)blockIdx.x;
    const int t = (int)threadIdx.x;

    size_t gi = ((size_t)b * NN + m) * QQ + t;
    float hv = h_io[gi];
    float ie = ieff[gi];

    sp[t] = hv * ie;
    sq[t] = ie * ie;
    __syncthreads();
    if (t < 32) {
        const float* a = (t < 16) ? sp : sq;
        int j = t & 7;
        int base = (t & 8) ? 128 : 0;
        float r = a[base + j];
        for (int i = 8; i < 128; i += 8) r = r + a[base + i + j];
        rs[t] = r;
    }
    __syncthreads();
    if (t == 0) {
        float d0 = ((rs[0] + rs[1]) + (rs[2] + rs[3])) + ((rs[4] + rs[5]) + (rs[6] + rs[7]));
        float d1 = ((rs[8] + rs[9]) + (rs[10] + rs[11])) + ((rs[12] + rs[13]) + (rs[14] + rs[15]));
        float dot = d0 + d1;
        float u0 = ((rs[16] + rs[17]) + (rs[18] + rs[19])) + ((rs[20] + rs[21]) + (rs[22] + rs[23]));
        float u1 = ((rs[24] + rs[25]) + (rs[26] + rs[27])) + ((rs[28] + rs[29]) + (rs[30] + rs[31]));
        float un = u0 + u1;
        sc[0] = dot / (un + 1e-12f);
    }
    __syncthreads();
    float c = sc[0];
    float tmp = c * ie;
    float h2 = hv - tmp;
    float r = (h2 > 0.0f) ? h2 : 0.0f;
    sp[t] = r * r;
    __syncthreads();
    if (t < 16) {
        int j = t & 7;
        int base = (t & 8) ? 128 : 0;
        float rr = sp[base + j];
        for (int i = 8; i < 128; i += 8) rr = rr + sp[base + i + j];
        rs[t] = rr;
    }
    __syncthreads();
    if (t == 0) {
        float n0 = ((rs[0] + rs[1]) + (rs[2] + rs[3])) + ((rs[4] + rs[5]) + (rs[6] + rs[7]));
        float n1 = ((rs[8] + rs[9]) + (rs[10] + rs[11])) + ((rs[12] + rs[13]) + (rs[14] + rs[15]));
        float nn = n0 + n1;
        float den = (float)sqrt((double)nn);
        if (den < 1e-8f) den = 1e-8f;
        sc[1] = den;
    }
    __syncthreads();
    h_io[gi] = r / sc[1];
}

// ---------------------------------------------------------------------------
extern "C" void kernel_launch(void* const* d_in, const int* in_sizes, int n_in,
                              void* d_out, int out_size, void* d_ws, size_t ws_size,
                              hipStream_t stream)
{
    const float* h0     = 0;
    const float* adj    = 0;
    const float* act_in = 0;
    for (int i = 0; i < n_in; ++i) {
        if (in_sizes[i] == BB * NN * QQ)      h0     = (const float*)d_in[i];
        else if (in_sizes[i] == BB * NN * NN) adj    = (const float*)d_in[i];
        else if (in_sizes[i] == BB * NN)      act_in = (const float*)d_in[i];
    }
    float* out = (float*)d_out;

    char* ws = (char*)d_ws;
    size_t off = 0;
    float* ieff = (float*)(ws + off); off += (size_t)BB * NN * QQ * 4;      // 4 MB
    float* pe0 = (float*)(ws + off); off += (size_t)CHUNKS * BB * NN * 4;   // 256 KB
    float* pi0 = (float*)(ws + off); off += (size_t)CHUNKS * BB * NN * 4;
    float* pe1 = (float*)(ws + off); off += (size_t)CHUNKS * BB * NN * 4;
    float* pi1 = (float*)(ws + off); off += (size_t)CHUNKS * BB * NN * 4;
    float* sum_e0 = (float*)(ws + off); off += (size_t)BB * NN * 4;
    float* sum_i0 = (float*)(ws + off); off += (size_t)BB * NN * 4;
    float* sum_e1 = (float*)(ws + off); off += (size_t)BB * NN * 4;
    float* sum_i1 = (float*)(ws + off); off += (size_t)BB * NN * 4;

    const size_t slice_sz = (size_t)BB * NN * QQ;

    colsum_part<<<dim3(NN / 256, CHUNKS, BB), 256, 0, stream>>>(
        adj, act_in, pe0, pi0, pe1, pi1);
    colsum_combine<<<dim3(BB * NN / 256), 256, 0, stream>>>(
        pe0, pi0, pe1, pi1, sum_e0, sum_i0, sum_e1, sum_i1);

    for (int it = 0; it < NUM_ITERS; ++it) {
        const float* act = (it == 0) ? act_in : (const float*)0;
        const float* se  = (it == 0) ? sum_e0 : sum_e1;
        const float* si  = (it == 0) ? sum_i0 : sum_i1;
        const float* h_prev = (it == 0) ? h0 : (out + (size_t)(it - 1) * slice_sz);
        float* h_cur = out + (size_t)it * slice_sz;

        // h_cur = h_prev + e_eff   (excite)
        gemm_fused<<<dim3(NN / 64, QQ / 32, BB), 256, 0, stream>>>(
            adj, h_prev, act, se, h_prev, h_cur, 0);
        // ieff from updated h     (inhibit)
        gemm_fused<<<dim3(NN / 64, QQ / 32, BB), 256, 0, stream>>>(
            adj, h_cur, act, si, (const float*)0, ieff, 1);
        // projection + relu + normalize (np-exact), in place
        project_kernel<<<dim3(NN, BB), 256, 0, stream>>>(h_cur, ieff);
    }
}

// Round 14
// 3771.930 us; speedup vs baseline: 2.2245x; 2.2245x over previous
//
#include <hip/hip_runtime.h>

#define NUM_ITERS 15
#define BB 2
#define NN 2048
#define QQ 256
#define CHUNKS 16          // colsum n-chunks of 128 rows

// ---------------------------------------------------------------------------
// Numerical contract (matches numpy-fp32 golden; verified absmax 0.00195 —
// LOAD-BEARING, do not relax):
//  - no FMA contraction (pragma clang fp contract(off))
//  - GEMM per output element: single fp32 accumulator, strictly ascending k,
//    round(mul) then round(add), final true division by max(sum,1)
//  - row reductions over q=256: numpy pairwise tree, order replicated exactly
//  - colsum: ascending-n in 16 chunks, combined ascending
//
// Session ledger (why this kernel is shaped this way):
// R4: gfx950 VGPR max=256; uncapped bounds + big unrolls -> scratch spill.
// R5: 1 wave/SIMD latency-bound under COMPILER scheduling.
// R6: counted waitcnt regions need "memory" clobbers + sched_barrier fences.
// R7: counted-lgkm 4x2/8-wave sits AT the ~74-85 B/cyc/CU LDS-pipe ceiling
//     (per-lane byte charging; broadcasts NOT deduped).
// R8/R9: 4-wave 4x4 configs cap ~45 B/cyc regardless of issue depth.
// R10: asm-pinned 72-reg rotating files crash/break counted vmcnt.
// R11: plain-C++ register pipelines collapsed by regalloc (VGPR 56, 338us).
// R12 (CHAMPION, 3775us total / 145us top gemm): 64x32 tile x 2 independent
//     blocks/CU overlaps barrier drain; ~90% of the LDS-pipe floor.
// R13: H-direct-from-global hybrid -> scratch spill (WRITE 375MB; compiler
//     left rotating slots runtime-indexed). FIVE structural escapes failed.
// R14: exact revert to R12. This is the practical ceiling of this structure:
//     fp32 (no MFMA) -> VALU floor 55us/gemm; operand delivery floor at
//     3 B/MAC over the measured LDS pipe ~= 130us/gemm; achieved ~120 avg.
// ---------------------------------------------------------------------------

typedef float f4v __attribute__((ext_vector_type(4)));
typedef float f2v __attribute__((ext_vector_type(2)));
typedef __attribute__((address_space(3))) const float4 lds_cf4;

#define DSR128(d, a, IMM) asm volatile("ds_read_b128 %0, %1 offset:" #IMM : "=v"(d) : "v"(a) : "memory")
#define DSR64(d, a, IMM)  asm volatile("ds_read_b64 %0, %1 offset:" #IMM  : "=v"(d) : "v"(a) : "memory")
#define LGKM(N)           asm volatile("s_waitcnt lgkmcnt(" #N ")" ::: "memory")

__global__ __launch_bounds__(256) void colsum_part(
    const float* __restrict__ adj, const float* __restrict__ act,
    float* __restrict__ pe0, float* __restrict__ pi0,
    float* __restrict__ pe1, float* __restrict__ pi1)
{
#pragma clang fp contract(off)
    const int b = (int)blockIdx.z;
    const int c = (int)blockIdx.y;
    const int m = (int)blockIdx.x * 256 + (int)threadIdx.x;
    const float* src = adj + (size_t)b * NN * NN;
    const float* ab  = act + (size_t)b * NN;
    float se0 = 0.0f, si0 = 0.0f, se1 = 0.0f, si1 = 0.0f;
    const int n0 = c * (NN / CHUNKS);
    for (int n = n0; n < n0 + NN / CHUNKS; ++n) {
        float x = src[(size_t)n * NN + m];
        float e = (x > 0.5f) ? x : 0.0f;
        float v = 1.0f - x;
        float iv = (v > 0.5f) ? v : 0.0f;
        float av = ab[n];
        se1 = se1 + e;
        si1 = si1 + iv;
        se0 = se0 + e * av;
        si0 = si0 + iv * av;
    }
    size_t o = ((size_t)c * BB + b) * NN + m;
    pe0[o] = se0; pi0[o] = si0; pe1[o] = se1; pi1[o] = si1;
}

__global__ __launch_bounds__(256) void colsum_combine(
    const float* __restrict__ pe0, const float* __restrict__ pi0,
    const float* __restrict__ pe1, const float* __restrict__ pi1,
    float* __restrict__ se0, float* __restrict__ si0,
    float* __restrict__ se1, float* __restrict__ si1)
{
#pragma clang fp contract(off)
    const int i = (int)blockIdx.x * 256 + (int)threadIdx.x;   // 0..BB*NN-1
    float a = 0.0f, bb = 0.0f, cc = 0.0f, dd = 0.0f;
    for (int c = 0; c < CHUNKS; ++c) {
        size_t o = (size_t)c * (BB * NN) + i;
        a  = a  + pe0[o];
        bb = bb + pi0[o];
        cc = cc + pe1[o];
        dd = dd + pi1[o];
    }
    se0[i] = a; si0[i] = bb; se1[i] = cc; si1[i] = dd;
}

// ---------------------------------------------------------------------------
// Fused thresholded GEMM, np-fp32-exact per-element chain:
//   C[m][q] = sum_k (thr(adj[k][m]) * act[k]) * hsrc[k][q]   (ascending k)
//   mode 0: dst = h_old + C/max(sum,1);  mode 1: dst = C/max(sum,1)
//
// v12/v14: 64x32 tile, BK=64, 256 threads (4 waves), 4x2 microtile, dbuf
// LDS, counted-lgkm inner loop (16 groups of 4 kk; issue next group's 8
// ds_reads, lgkmcnt(8), sched_barrier, 32 MACs).
// Grid 512 blocks = 2 independent blocks/CU (LDS 52KB x2 = 104KB fits):
// independent barriers overlap each other's staging drain.
// ---------------------------------------------------------------------------
__global__ __launch_bounds__(256, 4) void gemm_fused(
    const float* __restrict__ adj,
    const float* __restrict__ hsrc,
    const float* act,
    const float* __restrict__ sums,
    const float* h_old,
    float* __restrict__ dst,
    int mode)
{
#pragma clang fp contract(off)
    __shared__ float4 W2[2][64][17];   // [dbuf][kk][16 f4 m-cols +pad] row=272B
    __shared__ float4 H2[2][64][9];    // [dbuf][kk][8 f4 q-cols +pad]  row=144B

    const int b  = (int)blockIdx.z;
    const int m0 = (int)blockIdx.x * 64;
    const int q0 = (int)blockIdx.y * 32;
    const int tid = (int)threadIdx.x;
    const int tq  = tid & 15;      // q-group: cols q0 + tq*2 .. +1
    const int tm  = tid >> 4;      // m-group: rows m0 + tm*4 .. +3

    const float* adjb = adj + (size_t)b * NN * NN;
    const float* hb   = hsrc + (size_t)b * NN * QQ;
    const float* ab   = (act != 0) ? (act + (size_t)b * NN) : (const float*)0;

    // true LDS byte offsets via addrspace(3) pointers (32-bit)
    const unsigned wbase = (unsigned)(uintptr_t)(lds_cf4*)&W2[0][0][0] + (unsigned)tm * 16u;
    const unsigned hbase = (unsigned)(uintptr_t)(lds_cf4*)&H2[0][0][0] + (unsigned)tq * 8u;

    float acc[4][2];
    #pragma unroll
    for (int i = 0; i < 4; ++i)
        #pragma unroll
        for (int j = 0; j < 2; ++j)
            acc[i][j] = 0.0f;

    float4 wreg[4], hreg[2];

    // issue global loads for K-tile starting at kbase into regs
    auto stage_load = [&](int kbase) {
#pragma clang fp contract(off)
        #pragma unroll
        for (int j = 0; j < 4; ++j) {          // W: 64kk x 16 seg = 1024 f4
            int idx = tid + j * 256;
            int kk  = idx >> 4;                // 0..63
            int seg = idx & 15;                // 0..15
            wreg[j] = *(const float4*)(adjb + (size_t)(kbase + kk) * NN + m0 + seg * 4);
        }
        #pragma unroll
        for (int j = 0; j < 2; ++j) {          // H: 64kk x 8 seg = 512 f4
            int idx = tid + j * 256;
            int kk  = idx >> 3;                // 0..63
            int seg = idx & 7;                 // 0..7
            hreg[j] = *(const float4*)(hb + (size_t)(kbase + kk) * QQ + q0 + seg * 4);
        }
    };

    // threshold + write regs -> LDS buffer sbuf (kbase for act indexing)
    auto stage_store = [&](int sbuf, int kbase) {
#pragma clang fp contract(off)
        #pragma unroll
        for (int j = 0; j < 4; ++j) {
            int idx = tid + j * 256;
            int kk  = idx >> 4;
            int seg = idx & 15;
            float4 x = wreg[j];
            float4 w;
            if (mode == 0) {
                w.x = (x.x > 0.5f) ? x.x : 0.0f;
                w.y = (x.y > 0.5f) ? x.y : 0.0f;
                w.z = (x.z > 0.5f) ? x.z : 0.0f;
                w.w = (x.w > 0.5f) ? x.w : 0.0f;
            } else {
                float vx = 1.0f - x.x; w.x = (vx > 0.5f) ? vx : 0.0f;
                float vy = 1.0f - x.y; w.y = (vy > 0.5f) ? vy : 0.0f;
                float vz = 1.0f - x.z; w.z = (vz > 0.5f) ? vz : 0.0f;
                float vw = 1.0f - x.w; w.w = (vw > 0.5f) ? vw : 0.0f;
            }
            if (ab != 0) {
                float av = ab[kbase + kk];
                w.x = w.x * av; w.y = w.y * av; w.z = w.z * av; w.w = w.w * av;
            }
            W2[sbuf][kk][seg] = w;
        }
        #pragma unroll
        for (int j = 0; j < 2; ++j) {
            int idx = tid + j * 256;
            int kk  = idx >> 3;
            int seg = idx & 7;
            H2[sbuf][kk][seg] = hreg[j];
        }
    };

    // compute one K-tile from LDS buffer cbuf; counted-lgkm group pipeline
    // (W row stride 272B, group stride 1088B; H row 144B, group 576B)
    auto compute = [&](int cbuf) {
#pragma clang fp contract(off)
        __builtin_amdgcn_sched_barrier(0);     // fence: nothing enters region
        const unsigned wa = wbase + (unsigned)cbuf * 17408u;
        const unsigned ha = hbase + (unsigned)cbuf * 9216u;
        f4v w[2][4];
        f2v h[2][4];
        // prologue: group 0 (kk 0..3) into set 0
        DSR128(w[0][0], wa, 0);   DSR128(w[0][1], wa, 272);
        DSR128(w[0][2], wa, 544); DSR128(w[0][3], wa, 816);
        DSR64 (h[0][0], ha, 0);   DSR64 (h[0][1], ha, 144);
        DSR64 (h[0][2], ha, 288); DSR64 (h[0][3], ha, 432);
        #pragma unroll
        for (int g = 0; g < 16; ++g) {
            const int s = g & 1, sn = s ^ 1;
            if (g < 15) {
                unsigned awn = wa + (unsigned)((g + 1) * 1088);
                unsigned ahn = ha + (unsigned)((g + 1) * 576);
                DSR128(w[sn][0], awn, 0);   DSR128(w[sn][1], awn, 272);
                DSR128(w[sn][2], awn, 544); DSR128(w[sn][3], awn, 816);
                DSR64 (h[sn][0], ahn, 0);   DSR64 (h[sn][1], ahn, 144);
                DSR64 (h[sn][2], ahn, 288); DSR64 (h[sn][3], ahn, 432);
                LGKM(8);                       // prev group done, 8 in flight
            } else {
                LGKM(0);                       // tile epilogue: drain
            }
            __builtin_amdgcn_sched_barrier(0); // MACs stay below the wait
            #pragma unroll
            for (int j = 0; j < 4; ++j) {      // kk = 4g+j, ascending
                f4v wv = w[s][j];
                f2v hv = h[s][j];
                #pragma unroll
                for (int i = 0; i < 4; ++i) {
                    acc[i][0] = acc[i][0] + wv[i] * hv[0];
                    acc[i][1] = acc[i][1] + wv[i] * hv[1];
                }
            }
        }
        __builtin_amdgcn_sched_barrier(0);     // fence: nothing leaves region
    };

    // prologue: tile 0 into LDS buffer 0
    stage_load(0);
    stage_store(0, 0);
    __syncthreads();

    int cur = 0;
    #pragma clang loop unroll(disable)
    for (int k0 = 0; k0 < NN; k0 += 64) {
        const int knext = k0 + 64;
        if (knext < NN) stage_load(knext);     // VMEM issue, hidden by compute
        compute(cur);
        if (knext < NN) {
            stage_store(cur ^ 1, knext);       // writes the OTHER buffer
            __syncthreads();                   // one barrier per tile
            cur ^= 1;
        }
    }

    // epilogue: true division, optional h_old add, float2 stores
    #pragma unroll
    for (int i = 0; i < 4; ++i) {
        int row = m0 + tm * 4 + i;
        float s = sums[b * NN + row];
        if (s < 1.0f) s = 1.0f;
        float v0 = acc[i][0] / s;
        float v1 = acc[i][1] / s;
        size_t g = ((size_t)b * NN + row) * QQ + q0 + tq * 2;
        float2 o;
        if (mode == 0) {
            float2 ho = *(const float2*)(h_old + g);
            o.x = ho.x + v0; o.y = ho.y + v1;
        } else {
            o.x = v0; o.y = v1;
        }
        *(float2*)(dst + g) = o;
    }
}

// ---------------------------------------------------------------------------
// Projection + relu + L2-normalize, np-fp32-exact, in place on h_io.
// ---------------------------------------------------------------------------
__global__ __launch_bounds__(256) void project_kernel(
    float* h_io, const float* __restrict__ ieff)
{
#pragma clang fp contract(off)
    __shared__ float sp[256];
    __shared__ float sq[256];
    __shared__ float rs[32];
    __shared__ float sc[2];
    const int b = (int)blockIdx.y;
    const int m = (int)blockIdx.x;
    const int t = (int)threadIdx.x;

    size_t gi = ((size_t)b * NN + m) * QQ + t;
    float hv = h_io[gi];
    float ie = ieff[gi];

    sp[t] = hv * ie;
    sq[t] = ie * ie;
    __syncthreads();
    if (t < 32) {
        const float* a = (t < 16) ? sp : sq;
        int j = t & 7;
        int base = (t & 8) ? 128 : 0;
        float r = a[base + j];
        for (int i = 8; i < 128; i += 8) r = r + a[base + i + j];
        rs[t] = r;
    }
    __syncthreads();
    if (t == 0) {
        float d0 = ((rs[0] + rs[1]) + (rs[2] + rs[3])) + ((rs[4] + rs[5]) + (rs[6] + rs[7]));
        float d1 = ((rs[8] + rs[9]) + (rs[10] + rs[11])) + ((rs[12] + rs[13]) + (rs[14] + rs[15]));
        float dot = d0 + d1;
        float u0 = ((rs[16] + rs[17]) + (rs[18] + rs[19])) + ((rs[20] + rs[21]) + (rs[22] + rs[23]));
        float u1 = ((rs[24] + rs[25]) + (rs[26] + rs[27])) + ((rs[28] + rs[29]) + (rs[30] + rs[31]));
        float un = u0 + u1;
        sc[0] = dot / (un + 1e-12f);
    }
    __syncthreads();
    float c = sc[0];
    float tmp = c * ie;
    float h2 = hv - tmp;
    float r = (h2 > 0.0f) ? h2 : 0.0f;
    sp[t] = r * r;
    __syncthreads();
    if (t < 16) {
        int j = t & 7;
        int base = (t & 8) ? 128 : 0;
        float rr = sp[base + j];
        for (int i = 8; i < 128; i += 8) rr = rr + sp[base + i + j];
        rs[t] = rr;
    }
    __syncthreads();
    if (t == 0) {
        float n0 = ((rs[0] + rs[1]) + (rs[2] + rs[3])) + ((rs[4] + rs[5]) + (rs[6] + rs[7]));
        float n1 = ((rs[8] + rs[9]) + (rs[10] + rs[11])) + ((rs[12] + rs[13]) + (rs[14] + rs[15]));
        float nn = n0 + n1;
        float den = (float)sqrt((double)nn);
        if (den < 1e-8f) den = 1e-8f;
        sc[1] = den;
    }
    __syncthreads();
    h_io[gi] = r / sc[1];
}

// ---------------------------------------------------------------------------
extern "C" void kernel_launch(void* const* d_in, const int* in_sizes, int n_in,
                              void* d_out, int out_size, void* d_ws, size_t ws_size,
                              hipStream_t stream)
{
    const float* h0     = 0;
    const float* adj    = 0;
    const float* act_in = 0;
    for (int i = 0; i < n_in; ++i) {
        if (in_sizes[i] == BB * NN * QQ)      h0     = (const float*)d_in[i];
        else if (in_sizes[i] == BB * NN * NN) adj    = (const float*)d_in[i];
        else if (in_sizes[i] == BB * NN)      act_in = (const float*)d_in[i];
    }
    float* out = (float*)d_out;

    char* ws = (char*)d_ws;
    size_t off = 0;
    float* ieff = (float*)(ws + off); off += (size_t)BB * NN * QQ * 4;      // 4 MB
    float* pe0 = (float*)(ws + off); off += (size_t)CHUNKS * BB * NN * 4;   // 256 KB
    float* pi0 = (float*)(ws + off); off += (size_t)CHUNKS * BB * NN * 4;
    float* pe1 = (float*)(ws + off); off += (size_t)CHUNKS * BB * NN * 4;
    float* pi1 = (float*)(ws + off); off += (size_t)CHUNKS * BB * NN * 4;
    float* sum_e0 = (float*)(ws + off); off += (size_t)BB * NN * 4;
    float* sum_i0 = (float*)(ws + off); off += (size_t)BB * NN * 4;
    float* sum_e1 = (float*)(ws + off); off += (size_t)BB * NN * 4;
    float* sum_i1 = (float*)(ws + off); off += (size_t)BB * NN * 4;

    const size_t slice_sz = (size_t)BB * NN * QQ;

    colsum_part<<<dim3(NN / 256, CHUNKS, BB), 256, 0, stream>>>(
        adj, act_in, pe0, pi0, pe1, pi1);
    colsum_combine<<<dim3(BB * NN / 256), 256, 0, stream>>>(
        pe0, pi0, pe1, pi1, sum_e0, sum_i0, sum_e1, sum_i1);

    for (int it = 0; it < NUM_ITERS; ++it) {
        const float* act = (it == 0) ? act_in : (const float*)0;
        const float* se  = (it == 0) ? sum_e0 : sum_e1;
        const float* si  = (it == 0) ? sum_i0 : sum_i1;
        const float* h_prev = (it == 0) ? h0 : (out + (size_t)(it - 1) * slice_sz);
        float* h_cur = out + (size_t)it * slice_sz;

        // h_cur = h_prev + e_eff   (excite)
        gemm_fused<<<dim3(NN / 64, QQ / 32, BB), 256, 0, stream>>>(
            adj, h_prev, act, se, h_prev, h_cur, 0);
        // ieff from updated h     (inhibit)
        gemm_fused<<<dim3(NN / 64, QQ / 32, BB), 256, 0, stream>>>(
            adj, h_cur, act, si, (const float*)0, ieff, 1);
        // projection + relu + normalize (np-exact), in place
        project_kernel<<<dim3(NN, BB), 256, 0, stream>>>(h_cur, ieff);
    }
}